// Round 11
// baseline (195.734 us; speedup 1.0000x reference)
//
#include <hip/hip_runtime.h>

#define THREADS 256
typedef float v2f __attribute__((ext_vector_type(2)));

// tanh on 2 SAMPLES packed in a v2f: 3 pk VALU + 4 TRANS (2 per sample)
__device__ __forceinline__ v2f tanh2(v2f x) {
    v2f xs = x * 2.885390081777927f;                // 2*log2(e), scalar splat
    v2f e  = { __builtin_amdgcn_exp2f(xs.x),
               __builtin_amdgcn_exp2f(xs.y) };
    v2f ep = e + 1.0f;
    v2f r  = { __builtin_amdgcn_rcpf(ep.x),
               __builtin_amdgcn_rcpf(ep.y) };
    return (v2f){-2.0f, -2.0f} * r + 1.0f;
}

// Sample-major packing: x[k] holds feature k of TWO samples. Every weight is a
// wave-uniform scalar -> single-SGPR splat operand on v_pk_fma_f32 (no pair-
// building v_movs, unlike output-pair packing). 1-D static arrays only (R10's
// 2-D [NS][16] form scratch-spilled at VGPR=36).
template<int IN, int OUT>
__device__ __forceinline__ void dense(const v2f* x, v2f* y,
                                      const float* __restrict__ W,
                                      const float* __restrict__ b) {
#pragma unroll
    for (int j = 0; j < OUT; ++j) {
        v2f acc = { b[j], b[j] };                   // sgpr splat
#pragma unroll
        for (int k = 0; k < IN; ++k)
            acc += x[k] * W[k * OUT + j];           // pk_fma, scalar weight
        y[j] = tanh2(acc);
    }
}

__global__ __launch_bounds__(THREADS, 4) void qcnn_fused(
        const float* __restrict__ inputs,
        const float* __restrict__ W_fm, const float* __restrict__ b_fm,
        const float* __restrict__ W1,  const float* __restrict__ b1,
        const float* __restrict__ Wp1, const float* __restrict__ bp1,
        const float* __restrict__ W2,  const float* __restrict__ b2,
        const float* __restrict__ Wp2, const float* __restrict__ bp2,
        const float* __restrict__ W3,  const float* __restrict__ b3,
        const float* __restrict__ protos,
        const float* __restrict__ Wh,  const float* __restrict__ bh,
        float* __restrict__ out, int B) {
    const int t0 = blockIdx.x * THREADS + threadIdx.x;
    const int T  = gridDim.x * THREADS;
    const int iA = t0, iB = t0 + T;                 // two coalesced sample streams
    const bool vA = iA < B, vB = iB < B;

    v2f xa[16], xb[16];
    {
        const float4* pa = reinterpret_cast<const float4*>(inputs) + (size_t)(vA ? iA : 0) * 2;
        const float4* pb = reinterpret_cast<const float4*>(inputs) + (size_t)(vB ? iB : 0) * 2;
        float4 a0 = pa[0], a1 = pa[1], b0 = pb[0], b1 = pb[1];
        xa[0] = (v2f){a0.x, b0.x}; xa[1] = (v2f){a0.y, b0.y};
        xa[2] = (v2f){a0.z, b0.z}; xa[3] = (v2f){a0.w, b0.w};
        xa[4] = (v2f){a1.x, b1.x}; xa[5] = (v2f){a1.y, b1.y};
        xa[6] = (v2f){a1.z, b1.z}; xa[7] = (v2f){a1.w, b1.w};
    }

    dense<8, 16>(xa, xb, W_fm, b_fm);  // feature_map
    dense<16, 16>(xb, xa, W1, b1);     // conv1
    dense<16, 12>(xa, xb, Wp1, bp1);   // pool1
    dense<12, 8>(xb, xa, W2, b2);      // conv2
    dense<8, 4>(xa, xb, Wp2, bp2);     // pool2
    dense<4, 4>(xb, xa, W3, b3);       // conv3 -> xa[0..3] (both samples)

    // head x-part + RBF features vs 10 prototypes (GAMMA = 1), both samples packed
    v2f acc = { bh[0], bh[0] };
#pragma unroll
    for (int k = 0; k < 4; ++k) acc += xa[k] * Wh[k];
#pragma unroll
    for (int j = 0; j < 10; ++j) {
        v2f d2 = { 0.0f, 0.0f };
#pragma unroll
        for (int k = 0; k < 4; ++k) {
            v2f d = xa[k] - protos[j * 4 + k];      // pk sub, scalar splat
            d2 += d * d;                            // pk_fma
        }
        v2f d2s = d2 * -1.4426950408889634f;        // -log2e
        v2f kf = { __builtin_amdgcn_exp2f(d2s.x),
                   __builtin_amdgcn_exp2f(d2s.y) };
        acc += kf * Wh[4 + j];                      // pk_fma, scalar weight
    }
    // sigmoid per sample
    v2f as = acc * -1.4426950408889634f;
    float eA = __builtin_amdgcn_exp2f(as.x);
    float eB = __builtin_amdgcn_exp2f(as.y);
    if (vA) out[iA] = __builtin_amdgcn_rcpf(1.0f + eA);
    if (vB) out[iB] = __builtin_amdgcn_rcpf(1.0f + eB);
}

extern "C" void kernel_launch(void* const* d_in, const int* in_sizes, int n_in,
                              void* d_out, int out_size, void* d_ws, size_t ws_size,
                              hipStream_t stream) {
    const float* inputs = (const float*)d_in[0];
    float* out = (float*)d_out;
    const int B = in_sizes[0] / 8;
    const int blocks = (B + THREADS * 2 - 1) / (THREADS * 2);
    qcnn_fused<<<blocks, THREADS, 0, stream>>>(
        inputs,
        (const float*)d_in[1],  (const float*)d_in[2],
        (const float*)d_in[3],  (const float*)d_in[4],
        (const float*)d_in[5],  (const float*)d_in[6],
        (const float*)d_in[7],  (const float*)d_in[8],
        (const float*)d_in[9],  (const float*)d_in[10],
        (const float*)d_in[11], (const float*)d_in[12],
        (const float*)d_in[13],
        (const float*)d_in[14], (const float*)d_in[15],
        out, B);
}

// Round 12
// 195.112 us; speedup vs baseline: 1.0032x; 1.0032x over previous
//
#include <hip/hip_runtime.h>

#define THREADS 256
typedef float v2f __attribute__((ext_vector_type(2)));

// tanh of one feature for TWO samples packed in v2f: 3 pk VALU + 4 TRANS
__device__ __forceinline__ v2f tanh2(v2f x) {
    v2f xs = x * 2.885390081777927f;                // 2*log2(e)
    v2f e  = { __builtin_amdgcn_exp2f(xs.x),
               __builtin_amdgcn_exp2f(xs.y) };
    v2f ep = e + 1.0f;
    v2f r  = { __builtin_amdgcn_rcpf(ep.x),
               __builtin_amdgcn_rcpf(ep.y) };
    return (v2f){-2.0f, -2.0f} * r + 1.0f;
}

// All layer state in NAMED v2f scalars (A0..A15 / B0..B15): arrays of v2f (128B
// aggregates) get demoted to scratch by SROA (R10: VGPR=36, R11: VGPR=40, both
// ~4x slower); named scalars cannot be demoted. Weights are wave-uniform 32-bit
// scalars -> op_sel broadcast on v_pk_fma_f32, no pair-building v_movs.

#define DFM(dst,j) { float bb=b_fm[j]; v2f t={bb,bb}; \
  t += A0*W_fm[j];     t += A1*W_fm[16+j];  t += A2*W_fm[32+j];  t += A3*W_fm[48+j]; \
  t += A4*W_fm[64+j];  t += A5*W_fm[80+j];  t += A6*W_fm[96+j];  t += A7*W_fm[112+j]; \
  dst = tanh2(t); }

#define DC1(dst,j) { float bb=b1[j]; v2f t={bb,bb}; \
  t += B0*W1[j];       t += B1*W1[16+j];   t += B2*W1[32+j];   t += B3*W1[48+j]; \
  t += B4*W1[64+j];    t += B5*W1[80+j];   t += B6*W1[96+j];   t += B7*W1[112+j]; \
  t += B8*W1[128+j];   t += B9*W1[144+j];  t += B10*W1[160+j]; t += B11*W1[176+j]; \
  t += B12*W1[192+j];  t += B13*W1[208+j]; t += B14*W1[224+j]; t += B15*W1[240+j]; \
  dst = tanh2(t); }

#define DP1(dst,j) { float bb=bp1[j]; v2f t={bb,bb}; \
  t += A0*Wp1[j];      t += A1*Wp1[12+j];  t += A2*Wp1[24+j];  t += A3*Wp1[36+j]; \
  t += A4*Wp1[48+j];   t += A5*Wp1[60+j];  t += A6*Wp1[72+j];  t += A7*Wp1[84+j]; \
  t += A8*Wp1[96+j];   t += A9*Wp1[108+j]; t += A10*Wp1[120+j];t += A11*Wp1[132+j]; \
  t += A12*Wp1[144+j]; t += A13*Wp1[156+j];t += A14*Wp1[168+j];t += A15*Wp1[180+j]; \
  dst = tanh2(t); }

#define DC2(dst,j) { float bb=b2[j]; v2f t={bb,bb}; \
  t += B0*W2[j];      t += B1*W2[8+j];   t += B2*W2[16+j];  t += B3*W2[24+j]; \
  t += B4*W2[32+j];   t += B5*W2[40+j];  t += B6*W2[48+j];  t += B7*W2[56+j]; \
  t += B8*W2[64+j];   t += B9*W2[72+j];  t += B10*W2[80+j]; t += B11*W2[88+j]; \
  dst = tanh2(t); }

#define DP2(dst,j) { float bb=bp2[j]; v2f t={bb,bb}; \
  t += A0*Wp2[j];     t += A1*Wp2[4+j];  t += A2*Wp2[8+j];  t += A3*Wp2[12+j]; \
  t += A4*Wp2[16+j];  t += A5*Wp2[20+j]; t += A6*Wp2[24+j]; t += A7*Wp2[28+j]; \
  dst = tanh2(t); }

#define DC3(dst,j) { float bb=b3[j]; v2f t={bb,bb}; \
  t += B0*W3[j];      t += B1*W3[4+j];   t += B2*W3[8+j];   t += B3*W3[12+j]; \
  dst = tanh2(t); }

#define RBF(j) { \
  v2f e0=A0-protos[4*(j)], e1=A1-protos[4*(j)+1], e2=A2-protos[4*(j)+2], e3=A3-protos[4*(j)+3]; \
  v2f s = e0*e0; s += e1*e1; s += e2*e2; s += e3*e3; \
  v2f sc = s * -1.4426950408889634f; \
  v2f kf = { __builtin_amdgcn_exp2f(sc.x), __builtin_amdgcn_exp2f(sc.y) }; \
  acc += kf * Wh[4+(j)]; }

__global__ __launch_bounds__(THREADS, 4) void qcnn_fused(
        const float* __restrict__ inputs,
        const float* __restrict__ W_fm, const float* __restrict__ b_fm,
        const float* __restrict__ W1,  const float* __restrict__ b1,
        const float* __restrict__ Wp1, const float* __restrict__ bp1,
        const float* __restrict__ W2,  const float* __restrict__ b2,
        const float* __restrict__ Wp2, const float* __restrict__ bp2,
        const float* __restrict__ W3,  const float* __restrict__ b3,
        const float* __restrict__ protos,
        const float* __restrict__ Wh,  const float* __restrict__ bh,
        float* __restrict__ out, int B) {
    const int t0 = blockIdx.x * THREADS + threadIdx.x;
    const int T  = gridDim.x * THREADS;
    const int iA = t0, iB = t0 + T;                 // two coalesced sample streams
    const bool vA = iA < B, vB = iB < B;

    v2f A0,A1,A2,A3,A4,A5,A6,A7,A8,A9,A10,A11,A12,A13,A14,A15;
    v2f B0,B1,B2,B3,B4,B5,B6,B7,B8,B9,B10,B11,B12,B13,B14,B15;

    {
        const float4* pa = reinterpret_cast<const float4*>(inputs) + (size_t)(vA ? iA : 0) * 2;
        const float4* pb = reinterpret_cast<const float4*>(inputs) + (size_t)(vB ? iB : 0) * 2;
        float4 a0 = pa[0], a1 = pa[1], c0 = pb[0], c1 = pb[1];
        A0 = (v2f){a0.x, c0.x}; A1 = (v2f){a0.y, c0.y};
        A2 = (v2f){a0.z, c0.z}; A3 = (v2f){a0.w, c0.w};
        A4 = (v2f){a1.x, c1.x}; A5 = (v2f){a1.y, c1.y};
        A6 = (v2f){a1.z, c1.z}; A7 = (v2f){a1.w, c1.w};
    }

    // feature_map 8->16
    DFM(B0,0) DFM(B1,1) DFM(B2,2) DFM(B3,3) DFM(B4,4) DFM(B5,5) DFM(B6,6) DFM(B7,7)
    DFM(B8,8) DFM(B9,9) DFM(B10,10) DFM(B11,11) DFM(B12,12) DFM(B13,13) DFM(B14,14) DFM(B15,15)
    // conv1 16->16
    DC1(A0,0) DC1(A1,1) DC1(A2,2) DC1(A3,3) DC1(A4,4) DC1(A5,5) DC1(A6,6) DC1(A7,7)
    DC1(A8,8) DC1(A9,9) DC1(A10,10) DC1(A11,11) DC1(A12,12) DC1(A13,13) DC1(A14,14) DC1(A15,15)
    // pool1 16->12
    DP1(B0,0) DP1(B1,1) DP1(B2,2) DP1(B3,3) DP1(B4,4) DP1(B5,5)
    DP1(B6,6) DP1(B7,7) DP1(B8,8) DP1(B9,9) DP1(B10,10) DP1(B11,11)
    // conv2 12->8
    DC2(A0,0) DC2(A1,1) DC2(A2,2) DC2(A3,3) DC2(A4,4) DC2(A5,5) DC2(A6,6) DC2(A7,7)
    // pool2 8->4
    DP2(B0,0) DP2(B1,1) DP2(B2,2) DP2(B3,3)
    // conv3 4->4
    DC3(A0,0) DC3(A1,1) DC3(A2,2) DC3(A3,3)

    // head x-part + RBF features vs 10 prototypes (GAMMA = 1)
    float bh0 = bh[0];
    v2f acc = { bh0, bh0 };
    acc += A0*Wh[0]; acc += A1*Wh[1]; acc += A2*Wh[2]; acc += A3*Wh[3];
    RBF(0) RBF(1) RBF(2) RBF(3) RBF(4) RBF(5) RBF(6) RBF(7) RBF(8) RBF(9)

    // sigmoid per sample
    v2f as = acc * -1.4426950408889634f;
    float eA = __builtin_amdgcn_exp2f(as.x);
    float eB = __builtin_amdgcn_exp2f(as.y);
    if (vA) out[iA] = __builtin_amdgcn_rcpf(1.0f + eA);
    if (vB) out[iB] = __builtin_amdgcn_rcpf(1.0f + eB);
}

extern "C" void kernel_launch(void* const* d_in, const int* in_sizes, int n_in,
                              void* d_out, int out_size, void* d_ws, size_t ws_size,
                              hipStream_t stream) {
    const float* inputs = (const float*)d_in[0];
    float* out = (float*)d_out;
    const int B = in_sizes[0] / 8;
    const int blocks = (B + THREADS * 2 - 1) / (THREADS * 2);
    qcnn_fused<<<blocks, THREADS, 0, stream>>>(
        inputs,
        (const float*)d_in[1],  (const float*)d_in[2],
        (const float*)d_in[3],  (const float*)d_in[4],
        (const float*)d_in[5],  (const float*)d_in[6],
        (const float*)d_in[7],  (const float*)d_in[8],
        (const float*)d_in[9],  (const float*)d_in[10],
        (const float*)d_in[11], (const float*)d_in[12],
        (const float*)d_in[13],
        (const float*)d_in[14], (const float*)d_in[15],
        out, B);
}

// Round 13
// 58.115 us; speedup vs baseline: 3.3680x; 3.3573x over previous
//
#include <hip/hip_runtime.h>

#define THREADS 256
typedef float v2f __attribute__((ext_vector_type(2)));

// 4 tanh sharing ONE v_rcp via batched reciprocal.
// tanh(x) = 1 - 2/(e^{2x}+1). Clamp x<=10 (tanh(10)=1-4e-9, err << f32 eps of
// the result) so e^{2x} <= 4.9e8 and the 4-way product <= 5.5e34 (no overflow,
// no inf-poisoning of the shared reciprocal). TRANS per 4 tanh: 4 exp + 1 rcp
// (was 4+4). Rounding delta vs direct rcp ~1ulp; R8 proved >=1e-4 headroom.
__device__ __forceinline__ void tanh4(v2f a, v2f b, v2f* ya, v2f* yb) {
    const v2f TEN = {10.0f, 10.0f};
    a = __builtin_elementwise_min(a, TEN);
    b = __builtin_elementwise_min(b, TEN);
    v2f as = a * 2.885390081777927f;                // 2*log2(e)
    v2f bs = b * 2.885390081777927f;
    v2f qa = { __builtin_amdgcn_exp2f(as.x), __builtin_amdgcn_exp2f(as.y) };
    v2f qb = { __builtin_amdgcn_exp2f(bs.x), __builtin_amdgcn_exp2f(bs.y) };
    qa += 1.0f; qb += 1.0f;                          // q in [1, 4.9e8]
    float t01 = qa.x * qa.y, t23 = qb.x * qb.y;
    float I   = __builtin_amdgcn_rcpf(t01 * t23);    // one rcp for all four
    float I01 = I * t23, I23 = I * t01;
    v2f ra = { I01 * qa.y, I01 * qa.x };
    v2f rb = { I23 * qb.y, I23 * qb.x };
    *ya = (v2f){-2.0f, -2.0f} * ra + 1.0f;
    *yb = (v2f){-2.0f, -2.0f} * rb + 1.0f;
}

// y[j] = tanh(b[j] + sum_k x[k]*W[k][j]); OUT % 4 == 0 (16,16,12,8,4,4)
template<int IN, int OUT>
__device__ __forceinline__ void dense(const float* x, float* y,
                                      const float* __restrict__ W,
                                      const float* __restrict__ b) {
#pragma unroll
    for (int j = 0; j < OUT; j += 4) {
        v2f a01 = { b[j],     b[j + 1] };
        v2f a23 = { b[j + 2], b[j + 3] };
#pragma unroll
        for (int k = 0; k < IN; ++k) {
            v2f w01 = { W[k * OUT + j],     W[k * OUT + j + 1] };
            v2f w23 = { W[k * OUT + j + 2], W[k * OUT + j + 3] };
            a01 += w01 * x[k];
            a23 += w23 * x[k];
        }
        v2f t01, t23;
        tanh4(a01, a23, &t01, &t23);
        y[j] = t01.x; y[j + 1] = t01.y; y[j + 2] = t23.x; y[j + 3] = t23.y;
    }
}

__global__ __launch_bounds__(THREADS) void qcnn_fused(
        const float* __restrict__ inputs,
        const float* __restrict__ W_fm, const float* __restrict__ b_fm,
        const float* __restrict__ W1,  const float* __restrict__ b1,
        const float* __restrict__ Wp1, const float* __restrict__ bp1,
        const float* __restrict__ W2,  const float* __restrict__ b2,
        const float* __restrict__ Wp2, const float* __restrict__ bp2,
        const float* __restrict__ W3,  const float* __restrict__ b3,
        const float* __restrict__ protos,
        const float* __restrict__ Wh,  const float* __restrict__ bh,
        float* __restrict__ out, int B) {
    const int tid = blockIdx.x * THREADS + threadIdx.x;
    if (tid >= B) return;

    float xa[16], xb[16];

    const float4* in4 = reinterpret_cast<const float4*>(inputs) + (size_t)tid * 2;
    float4 v0 = in4[0], v1 = in4[1];
    xa[0] = v0.x; xa[1] = v0.y; xa[2] = v0.z; xa[3] = v0.w;
    xa[4] = v1.x; xa[5] = v1.y; xa[6] = v1.z; xa[7] = v1.w;

    dense<8, 16>(xa, xb, W_fm, b_fm);  // feature_map
    dense<16, 16>(xb, xa, W1, b1);     // conv1
    dense<16, 12>(xa, xb, Wp1, bp1);   // pool1
    dense<12, 8>(xb, xa, W2, b2);      // conv2
    dense<8, 4>(xa, xb, Wp2, bp2);     // pool2
    dense<4, 4>(xb, xa, W3, b3);       // conv3 -> xa[0..3]

    // head contribution of x, then RBF features vs 10 prototypes (GAMMA = 1)
    v2f ha = { bh[0], 0.0f };
    ha += (v2f){ xa[0], xa[1] } * (v2f){ Wh[0], Wh[1] };
    ha += (v2f){ xa[2], xa[3] } * (v2f){ Wh[2], Wh[3] };
    float acc = ha.x + ha.y;

#pragma unroll
    for (int j = 0; j < 10; j += 2) {
        v2f d2 = { 0.0f, 0.0f };
#pragma unroll
        for (int k = 0; k < 4; ++k) {
            v2f p = { protos[j * 4 + k], protos[(j + 1) * 4 + k] };
            v2f d = (v2f){ xa[k], xa[k] } - p;
            d2 += d * d;
        }
        v2f d2s = d2 * -1.4426950408889634f;        // -log2e
        float kf0 = __builtin_amdgcn_exp2f(d2s.x);  // exp(-d2)
        float kf1 = __builtin_amdgcn_exp2f(d2s.y);
        acc = fmaf(kf0, Wh[4 + j], acc);
        acc = fmaf(kf1, Wh[5 + j], acc);
    }
    // sigmoid
    float e = __builtin_amdgcn_exp2f(acc * -1.4426950408889634f);
    out[tid] = __builtin_amdgcn_rcpf(1.0f + e);
}

extern "C" void kernel_launch(void* const* d_in, const int* in_sizes, int n_in,
                              void* d_out, int out_size, void* d_ws, size_t ws_size,
                              hipStream_t stream) {
    const float* inputs = (const float*)d_in[0];
    float* out = (float*)d_out;
    const int B = in_sizes[0] / 8;
    const int blocks = (B + THREADS - 1) / THREADS;
    qcnn_fused<<<blocks, THREADS, 0, stream>>>(
        inputs,
        (const float*)d_in[1],  (const float*)d_in[2],
        (const float*)d_in[3],  (const float*)d_in[4],
        (const float*)d_in[5],  (const float*)d_in[6],
        (const float*)d_in[7],  (const float*)d_in[8],
        (const float*)d_in[9],  (const float*)d_in[10],
        (const float*)d_in[11], (const float*)d_in[12],
        (const float*)d_in[13],
        (const float*)d_in[14], (const float*)d_in[15],
        out, B);
}